// Round 7
// baseline (83.189 us; speedup 1.0000x reference)
//
#include <hip/hip_runtime.h>
#include <math.h>

#define BS   8192
#define D    1024
#define TPB  256      // 4 waves
#define NBLK 512      // co-resident by construction (<=256 VGPR -> >=2 blk/CU)
#define RPB  16       // rows per block
#define RPWV 4        // rows per wave
#define F4R  4        // float4 per lane per row (D/4/64)

typedef float floatx4 __attribute__((ext_vector_type(4)));

// Single persistent dispatch.
//  Phase 1 (per wave, 4 rows): load z,w,u once; butterfly-reduce wu,wz,w2;
//    tnh = tanh(wz+b); fold v = z + tnh*u; keep v,w in registers.
//  Publish block partial of sum(w^2) (agent-release) + arrive counter; t0
//    polls counter (512 pollers, equal work -> tiny contention window).
//  Every block redundantly sums the 512 partials in fixed order -> wnrm.
//  Finalize from registers: z_new = v + tnh*coef*w; log_det via identity
//    inner2 = inner + tnh*(wu + coef*w2)  (no re-reduction over z_new).
__global__ __launch_bounds__(TPB, 2) void planar_persistent(
    const float* __restrict__ z, const float* __restrict__ w,
    const float* __restrict__ u, const float* __restrict__ b,
    float* __restrict__ zout, float* __restrict__ ldout,
    float* __restrict__ partials, unsigned int* __restrict__ ctrl)
{
    const int t    = threadIdx.x;
    const int wv   = t >> 6;
    const int l    = t & 63;
    const int row0 = blockIdx.x * RPB + wv * RPWV;

    float4 wr[RPWV][F4R];
    float4 vr[RPWV][F4R];
    float  wu_s[RPWV], in_s[RPWV], w2_s[RPWV], th_s[RPWV];
    float  w2acc = 0.f;

#pragma unroll
    for (int r = 0; r < RPWV; ++r) {
        const int row = row0 + r;
        const float4* z4 = (const float4*)z + (size_t)row * (D / 4);
        const float4* w4 = (const float4*)w + (size_t)row * (D / 4);
        const float4* u4 = (const float4*)u + (size_t)row * (D / 4);
        float4 zv[F4R], uv[F4R];
#pragma unroll
        for (int k = 0; k < F4R; ++k) {
            const int j = l + (k << 6);
            zv[k]    = z4[j];
            wr[r][k] = w4[j];
            uv[k]    = u4[j];
        }
        float wu = 0.f, wz = 0.f, w2 = 0.f;
#pragma unroll
        for (int k = 0; k < F4R; ++k) {
            const float4 a = wr[r][k];
            wu += a.x*uv[k].x + a.y*uv[k].y + a.z*uv[k].z + a.w*uv[k].w;
            wz += a.x*zv[k].x + a.y*zv[k].y + a.z*zv[k].z + a.w*zv[k].w;
            w2 += a.x*a.x + a.y*a.y + a.z*a.z + a.w*a.w;
        }
#pragma unroll
        for (int off = 32; off > 0; off >>= 1) {
            wu += __shfl_xor(wu, off, 64);
            wz += __shfl_xor(wz, off, 64);
            w2 += __shfl_xor(w2, off, 64);
        }
        const float inner = wz + b[row];
        const float tnh   = tanhf(inner);
#pragma unroll
        for (int k = 0; k < F4R; ++k) {
            vr[r][k].x = fmaf(tnh, uv[k].x, zv[k].x);
            vr[r][k].y = fmaf(tnh, uv[k].y, zv[k].y);
            vr[r][k].z = fmaf(tnh, uv[k].z, zv[k].z);
            vr[r][k].w = fmaf(tnh, uv[k].w, zv[k].w);
        }
        wu_s[r] = wu; in_s[r] = inner; w2_s[r] = w2; th_s[r] = tnh;
        w2acc += w2;   // wave-uniform after butterfly
    }

    // ---- publish block partial of sum(w^2), arrive, poll ----
    __shared__ float sw[4], sg[4];
    if (l == 0) sw[wv] = w2acc;
    __syncthreads();                                   // A: sw ready
    if (t == 0) {
        const float p = sw[0] + sw[1] + sw[2] + sw[3];
        __hip_atomic_store(&partials[blockIdx.x], p, __ATOMIC_RELEASE,
                           __HIP_MEMORY_SCOPE_AGENT);
        __hip_atomic_fetch_add(&ctrl[0], 1u, __ATOMIC_ACQ_REL,
                               __HIP_MEMORY_SCOPE_AGENT);
        while (__hip_atomic_load(&ctrl[0], __ATOMIC_ACQUIRE,
                                 __HIP_MEMORY_SCOPE_AGENT) < NBLK)
            __builtin_amdgcn_s_sleep(16);
    }
    __syncthreads();                                   // B: barrier passed

    // ---- redundant deterministic sum of the 512 partials ----
    float gs = __hip_atomic_load(&partials[t], __ATOMIC_RELAXED,
                                 __HIP_MEMORY_SCOPE_AGENT)
             + __hip_atomic_load(&partials[t + TPB], __ATOMIC_RELAXED,
                                 __HIP_MEMORY_SCOPE_AGENT);
#pragma unroll
    for (int off = 32; off > 0; off >>= 1) gs += __shfl_xor(gs, off, 64);
    if (l == 0) sg[wv] = gs;
    __syncthreads();                                   // C: sg ready
    const float wnrm = sqrtf(sg[0] + sg[1] + sg[2] + sg[3]);

    // ---- finalize from registers ----
#pragma unroll
    for (int r = 0; r < RPWV; ++r) {
        const int   row  = row0 + r;
        const float wu   = wu_s[r];
        const float sp   = (wu > 0.f) ? (wu + log1pf(expf(-wu)))
                                      : log1pf(expf(wu));
        const float coef = (-1.f + sp - wu) / wnrm;
        const float tc   = th_s[r] * coef;
        floatx4* o4 = (floatx4*)zout + (size_t)row * (D / 4);
#pragma unroll
        for (int k = 0; k < F4R; ++k) {
            floatx4 o;
            o.x = fmaf(tc, wr[r][k].x, vr[r][k].x);
            o.y = fmaf(tc, wr[r][k].y, vr[r][k].y);
            o.z = fmaf(tc, wr[r][k].z, vr[r][k].z);
            o.w = fmaf(tc, wr[r][k].w, vr[r][k].w);
            __builtin_nontemporal_store(o, o4 + l + (k << 6));
        }
        if (l == 0) {
            const float s      = fmaf(coef, w2_s[r], wu);
            const float inner2 = fmaf(th_s[r], s, in_s[r]);
            const float th2    = tanhf(inner2);
            const float hp     = 1.f - th2 * th2;
            ldout[row] = logf(fabsf(fmaf(hp, s, 1.f)));
        }
    }
}

extern "C" void kernel_launch(void* const* d_in, const int* in_sizes, int n_in,
                              void* d_out, int out_size, void* d_ws, size_t ws_size,
                              hipStream_t stream) {
    const float* z = (const float*)d_in[0];
    const float* w = (const float*)d_in[1];
    const float* u = (const float*)d_in[2];
    const float* b = (const float*)d_in[3];

    float* out   = (float*)d_out;
    float* zout  = out;                    // [BS, D]
    float* ldout = out + (size_t)BS * D;   // [BS]

    float*        partials = (float*)d_ws;                   // [NBLK]
    unsigned int* ctrl     = (unsigned int*)(partials + NBLK); // [1]

    hipMemsetAsync(ctrl, 0, sizeof(unsigned int), stream);
    planar_persistent<<<NBLK, TPB, 0, stream>>>(z, w, u, b, zout, ldout,
                                                partials, ctrl);
}

// Round 8
// 29.793 us; speedup vs baseline: 2.7922x; 2.7922x over previous
//
#include <hip/hip_runtime.h>
#include <math.h>

#define BS   8192
#define D    1024
#define TPB  256      // 4 waves
#define NBLK 512      // co-resident: <=256 VGPR + 4-wave blocks -> >=2 blk/CU
#define RPB  16       // rows per block
#define RPWV 4        // rows per wave
#define F4R  4        // float4 per lane per row (D/4/64)
#define SENT 0xFFFFFFFFu   // NaN bit pattern; Σw^2 partial is always finite

typedef float floatx4 __attribute__((ext_vector_type(4)));

// Single persistent dispatch, RMW-free sentinel barrier.
//  1. load w rows -> registers; per-row w2 butterfly; publish block partial
//     of sum(w^2) with a RELAXED agent store (sc1 write-through, no fence).
//  2. load z,u rows; wu/wz butterflies; tnh = tanh(wz+b); fold v = z+tnh*u.
//     (this 64MB of traffic overlaps everyone's publish)
//  3. wait: each thread RELAXED agent-loads slots t, t+256 until non-sentinel
//     (sc1 reads at the LLC; no RMWs, no acquire invalidates). The loaded
//     values are the data -> no fence needed. Fixed-order reduce -> wnrm.
//  4. finalize from registers; log_det via inner2 = inner + tnh*(wu+coef*w2).
__global__ __launch_bounds__(TPB, 2) void planar_persistent(
    const float* __restrict__ z, const float* __restrict__ w,
    const float* __restrict__ u, const float* __restrict__ b,
    float* __restrict__ zout, float* __restrict__ ldout,
    unsigned int* __restrict__ partials)
{
    const int t    = threadIdx.x;
    const int wv   = t >> 6;
    const int l    = t & 63;
    const int row0 = blockIdx.x * RPB + wv * RPWV;

    // ---- phase 1: w loads, per-row w2, early publish ----
    float4 wr[RPWV][F4R];
    float  w2_s[RPWV];
    float  w2acc = 0.f;
#pragma unroll
    for (int r = 0; r < RPWV; ++r) {
        const float4* w4 = (const float4*)w + (size_t)(row0 + r) * (D / 4);
        float w2 = 0.f;
#pragma unroll
        for (int k = 0; k < F4R; ++k) {
            const float4 a = w4[l + (k << 6)];
            wr[r][k] = a;
            w2 += a.x*a.x + a.y*a.y + a.z*a.z + a.w*a.w;
        }
#pragma unroll
        for (int off = 32; off > 0; off >>= 1) w2 += __shfl_xor(w2, off, 64);
        w2_s[r] = w2;
        w2acc  += w2;
    }
    __shared__ float sw[4], sg[4];
    if (l == 0) sw[wv] = w2acc;
    __syncthreads();
    if (t == 0) {
        const float p = sw[0] + sw[1] + sw[2] + sw[3];
        __hip_atomic_store(&partials[blockIdx.x], __float_as_uint(p),
                           __ATOMIC_RELAXED, __HIP_MEMORY_SCOPE_AGENT);
    }

    // ---- phase 2: z,u loads, row reductions, fold v = z + tnh*u ----
    float4 vr[RPWV][F4R];
    float  wu_s[RPWV], in_s[RPWV], th_s[RPWV];
#pragma unroll
    for (int r = 0; r < RPWV; ++r) {
        const int row = row0 + r;
        const float4* z4 = (const float4*)z + (size_t)row * (D / 4);
        const float4* u4 = (const float4*)u + (size_t)row * (D / 4);
        float4 zv[F4R], uv[F4R];
#pragma unroll
        for (int k = 0; k < F4R; ++k) {
            zv[k] = z4[l + (k << 6)];
            uv[k] = u4[l + (k << 6)];
        }
        float wu = 0.f, wz = 0.f;
#pragma unroll
        for (int k = 0; k < F4R; ++k) {
            const float4 a = wr[r][k];
            wu += a.x*uv[k].x + a.y*uv[k].y + a.z*uv[k].z + a.w*uv[k].w;
            wz += a.x*zv[k].x + a.y*zv[k].y + a.z*zv[k].z + a.w*zv[k].w;
        }
#pragma unroll
        for (int off = 32; off > 0; off >>= 1) {
            wu += __shfl_xor(wu, off, 64);
            wz += __shfl_xor(wz, off, 64);
        }
        const float inner = wz + b[row];
        const float tnh   = tanhf(inner);
#pragma unroll
        for (int k = 0; k < F4R; ++k) {
            vr[r][k].x = fmaf(tnh, uv[k].x, zv[k].x);
            vr[r][k].y = fmaf(tnh, uv[k].y, zv[k].y);
            vr[r][k].z = fmaf(tnh, uv[k].z, zv[k].z);
            vr[r][k].w = fmaf(tnh, uv[k].w, zv[k].w);
        }
        wu_s[r] = wu; in_s[r] = inner; th_s[r] = tnh;
    }

    // ---- phase 3: sentinel-poll barrier (no RMW, no acquire) ----
    unsigned int u0, u1;
    for (;;) {
        u0 = __hip_atomic_load(&partials[t], __ATOMIC_RELAXED,
                               __HIP_MEMORY_SCOPE_AGENT);
        u1 = __hip_atomic_load(&partials[t + TPB], __ATOMIC_RELAXED,
                               __HIP_MEMORY_SCOPE_AGENT);
        if (u0 != SENT && u1 != SENT) break;
        __builtin_amdgcn_s_sleep(4);
    }
    float gs = __uint_as_float(u0) + __uint_as_float(u1);
#pragma unroll
    for (int off = 32; off > 0; off >>= 1) gs += __shfl_xor(gs, off, 64);
    if (l == 0) sg[wv] = gs;
    __syncthreads();
    const float wnrm = sqrtf(sg[0] + sg[1] + sg[2] + sg[3]);

    // ---- phase 4: finalize from registers ----
#pragma unroll
    for (int r = 0; r < RPWV; ++r) {
        const int   row  = row0 + r;
        const float wu   = wu_s[r];
        const float sp   = (wu > 0.f) ? (wu + log1pf(expf(-wu)))
                                      : log1pf(expf(wu));
        const float coef = (-1.f + sp - wu) / wnrm;
        const float tc   = th_s[r] * coef;
        floatx4* o4 = (floatx4*)zout + (size_t)row * (D / 4);
#pragma unroll
        for (int k = 0; k < F4R; ++k) {
            floatx4 o;
            o.x = fmaf(tc, wr[r][k].x, vr[r][k].x);
            o.y = fmaf(tc, wr[r][k].y, vr[r][k].y);
            o.z = fmaf(tc, wr[r][k].z, vr[r][k].z);
            o.w = fmaf(tc, wr[r][k].w, vr[r][k].w);
            __builtin_nontemporal_store(o, o4 + l + (k << 6));
        }
        if (l == 0) {
            const float s      = fmaf(coef, w2_s[r], wu);
            const float inner2 = fmaf(th_s[r], s, in_s[r]);
            const float th2    = tanhf(inner2);
            const float hp     = 1.f - th2 * th2;
            ldout[row] = logf(fabsf(fmaf(hp, s, 1.f)));
        }
    }
}

extern "C" void kernel_launch(void* const* d_in, const int* in_sizes, int n_in,
                              void* d_out, int out_size, void* d_ws, size_t ws_size,
                              hipStream_t stream) {
    const float* z = (const float*)d_in[0];
    const float* w = (const float*)d_in[1];
    const float* u = (const float*)d_in[2];
    const float* b = (const float*)d_in[3];

    float* out   = (float*)d_out;
    float* zout  = out;                    // [BS, D]
    float* ldout = out + (size_t)BS * D;   // [BS]

    unsigned int* partials = (unsigned int*)d_ws;   // [NBLK]

    hipMemsetAsync(partials, 0xFF, NBLK * sizeof(unsigned int), stream);
    planar_persistent<<<NBLK, TPB, 0, stream>>>(z, w, u, b, zout, ldout,
                                                partials);
}